// Round 2
// baseline (142.042 us; speedup 1.0000x reference)
//
#include <hip/hip_runtime.h>
#include <hip/hip_bf16.h>

#define B_ 16
#define U_ 64
#define T_ 128
#define H_ 4
#define E_ 128
#define HID_ 256

typedef __hip_bfloat16 bf16;

// ---------------- encoder kernel ----------------
// 128 threads/block, ENC_R rows per block. Fuses the 3-layer MLP plus the
// fw1 projection (layer "L3", no bias/relu) so the big intermediate never
// touches global memory. head_q gets its own block (enters at L3 only).
// ALL inputs are fp32 (reference dtypes). K output stored bf16 (internal fmt).
#define ENC_R 4

__device__ __forceinline__ void layer128(const float (*in)[128], float (*out)[128],
    const float* __restrict__ W, const float* __restrict__ Bb, int j, bool do_relu)
{
  float a[ENC_R];
  float bb = Bb[j];
  #pragma unroll
  for (int r=0;r<ENC_R;r++) a[r]=bb;
  #pragma unroll
  for (int ic=0; ic<4; ic++){
    float w[32];
    #pragma unroll
    for (int i=0;i<32;i++) w[i]=W[(ic*32+i)*128 + j];
    #pragma unroll
    for (int r=0;r<ENC_R;r++){
      float s=0.f;
      #pragma unroll
      for (int i=0;i<32;i++) s = fmaf(in[r][ic*32+i], w[i], s);
      a[r]+=s;
    }
  }
  #pragma unroll
  for (int r=0;r<ENC_R;r++) out[r][j] = do_relu ? fmaxf(a[r],0.f) : a[r];
}

__global__ __launch_bounds__(128) void enc_kernel(
  const float* __restrict__ uav, const float* __restrict__ task,
  const float* __restrict__ uw0, const float* __restrict__ ub0,
  const float* __restrict__ uw1, const float* __restrict__ ub1,
  const float* __restrict__ uw2, const float* __restrict__ ub2,
  const float* __restrict__ tw0, const float* __restrict__ tb0,
  const float* __restrict__ tw1, const float* __restrict__ tb1,
  const float* __restrict__ tw2, const float* __restrict__ tb2,
  const float* __restrict__ headq, const float* __restrict__ fw1,
  float* __restrict__ ueW, bf16* __restrict__ Kg, float* __restrict__ QhW)
{
  __shared__ float X[ENC_R][32];
  __shared__ float Ha[ENC_R][128];
  __shared__ float Hb[ENC_R][128];
  const int j = threadIdx.x;
  const int blk = blockIdx.x;

  const float *w0=nullptr,*b0=nullptr,*w1=nullptr,*b1=nullptr,*w2=nullptr,*b2=nullptr,*xin=nullptr;
  const float* fwbase;
  float* outF = nullptr;
  bf16*  outB = nullptr;
  bool only_last = false;
  int row0;

  if (blk < 256) {            // uav path: rows (b*U+u), output ueW fp32
    row0 = blk*ENC_R;
    xin = uav + row0*32;
    w0=uw0;b0=ub0;w1=uw1;b1=ub1;w2=uw2;b2=ub2;
    fwbase = fw1;             // fw1[:E]
    outF = ueW + row0*HID_;
  } else if (blk < 768) {     // task path: rows (b*T+t), output K bf16
    row0 = (blk-256)*ENC_R;
    xin = task + row0*32;
    w0=tw0;b0=tb0;w1=tw1;b1=tb1;w2=tw2;b2=tb2;
    fwbase = fw1 + 128*HID_;  // fw1[E:]
    outB = Kg + row0*HID_;
  } else {                    // head_q: only L3
    only_last = true;
    fwbase = fw1;
    outF = QhW;
  }

  if (!only_last) {
    for (int idx=j; idx<ENC_R*32; idx+=128){ int r=idx>>5, i=idx&31; X[r][i]=xin[idx]; }
    __syncthreads();
    // L0: 32 -> 128, relu
    {
      float w[32];
      #pragma unroll
      for (int i=0;i<32;i++) w[i]=w0[i*128 + j];
      float bb=b0[j];
      #pragma unroll
      for (int r=0;r<ENC_R;r++){
        float a=bb;
        #pragma unroll
        for (int i=0;i<32;i++) a = fmaf(X[r][i], w[i], a);
        Ha[r][j]=fmaxf(a,0.f);
      }
    }
    __syncthreads();
    layer128(Ha,Hb,w1,b1,j,true);    // L1 relu
    __syncthreads();
    layer128(Hb,Ha,w2,b2,j,false);   // L2 NO relu (reference: final linear)
    __syncthreads();
  } else {
    #pragma unroll
    for (int r=0;r<ENC_R;r++) Ha[r][j] = headq[r*128 + j];
    __syncthreads();
  }

  // L3: E(128) -> HID(256) with fw1 part; no bias (fb1 folded into logits base)
  #pragma unroll
  for (int o=0;o<2;o++){
    const int jo = o*128 + j;
    float a[ENC_R] = {0.f,0.f,0.f,0.f};
    #pragma unroll
    for (int ic=0; ic<4; ic++){
      float w[32];
      #pragma unroll
      for (int i=0;i<32;i++) w[i]=fwbase[(ic*32+i)*HID_ + jo];
      #pragma unroll
      for (int r=0;r<ENC_R;r++){
        float s=0.f;
        #pragma unroll
        for (int i=0;i<32;i++) s = fmaf(Ha[r][ic*32+i], w[i], s);
        a[r]+=s;
      }
    }
    #pragma unroll
    for (int r=0;r<ENC_R;r++){
      if (outF) outF[r*HID_ + jo] = a[r];
      else      outB[r*HID_ + jo] = __float2bfloat16(a[r]);
    }
  }
}

// ---------------- logits kernel ----------------
// Block = (u-tile of 8, h, b), 256 threads = 4 waves. Each wave owns 2 u-rows.
// K[b] staged per 64-t half in LDS ([t][d2] uints, stride 131 -> <=2-way banks).
// lanes index t; per-row base (ueW+QhW+fb1) and fw2 read as b128 broadcasts.
#define UTILE 8

__global__ __launch_bounds__(256) void logits_kernel(
  const float* __restrict__ ueW, const float* __restrict__ QhW,
  const bf16* __restrict__ Kg,
  const float* __restrict__ fb1, const float* __restrict__ fw2,
  const float* __restrict__ fb2, float* __restrict__ out)
{
  __shared__ unsigned int Kl[64*131];
  __shared__ float4 basebuf[4][2][64];
  __shared__ float4 w2buf[64];

  const int tid = threadIdx.x;
  const int wv = tid >> 6;
  const int lane = tid & 63;
  const int b = blockIdx.z, h = blockIdx.y;
  const int u0 = blockIdx.x * UTILE;

  {
    const float* Q = QhW + h*HID_;
    float4 q4 = *(const float4*)(Q + 4*lane);
    float4 f4 = ((const float4*)fb1)[lane];
    #pragma unroll
    for (int rr=0; rr<2; rr++){
      const int u = u0 + wv*2 + rr;
      const float* A = ueW + (b*U_ + u)*HID_;
      float4 a4 = *(const float4*)(A + 4*lane);
      basebuf[wv][rr][lane] = make_float4(a4.x+q4.x+f4.x, a4.y+q4.y+f4.y,
                                          a4.z+q4.z+f4.z, a4.w+q4.w+f4.w);
    }
    if (tid < 64) {
      w2buf[tid] = ((const float4*)fw2)[tid];
    }
  }
  const float fb2f = fb2[0];
  const unsigned int* Kgb = (const unsigned int*)Kg + b*T_*(HID_/2);

  const int tb = lane*131;
  const int obase0 = ((b*H_ + h)*U_ + (u0 + wv*2 + 0))*T_;
  const int obase1 = obase0 + T_;

  for (int half=0; half<2; half++){
    __syncthreads();  // basebuf ready / previous half's compute done
    for (int it = tid; it < 64*64; it += 256){
      int t = it >> 6, dq = it & 63;
      const uint2 v = ((const uint2*)(Kgb + (half*64 + t)*128))[dq];
      Kl[t*131 + 2*dq]     = v.x;
      Kl[t*131 + 2*dq + 1] = v.y;
    }
    __syncthreads();  // Kl ready
    float acc0 = 0.f, acc1 = 0.f;
    #pragma unroll 4
    for (int c=0; c<64; c++){
      const unsigned int k0 = Kl[tb + 2*c];
      const unsigned int k1 = Kl[tb + 2*c + 1];
      const float4 w4 = w2buf[c];
      const float4 p0 = basebuf[wv][0][c];
      const float4 p1 = basebuf[wv][1][c];
      const float x0 = __uint_as_float(k0 << 16);
      const float x1 = __uint_as_float(k0 & 0xffff0000u);
      const float x2 = __uint_as_float(k1 << 16);
      const float x3 = __uint_as_float(k1 & 0xffff0000u);
      acc0 = fmaf(fmaxf(p0.x + x0, 0.f), w4.x, acc0);
      acc0 = fmaf(fmaxf(p0.y + x1, 0.f), w4.y, acc0);
      acc0 = fmaf(fmaxf(p0.z + x2, 0.f), w4.z, acc0);
      acc0 = fmaf(fmaxf(p0.w + x3, 0.f), w4.w, acc0);
      acc1 = fmaf(fmaxf(p1.x + x0, 0.f), w4.x, acc1);
      acc1 = fmaf(fmaxf(p1.y + x1, 0.f), w4.y, acc1);
      acc1 = fmaf(fmaxf(p1.z + x2, 0.f), w4.z, acc1);
      acc1 = fmaf(fmaxf(p1.w + x3, 0.f), w4.w, acc1);
    }
    const int t = half*64 + lane;
    out[obase0 + t] = acc0 + fb2f;
    out[obase1 + t] = acc1 + fb2f;
  }
}

extern "C" void kernel_launch(void* const* d_in, const int* in_sizes, int n_in,
                              void* d_out, int out_size, void* d_ws, size_t ws_size,
                              hipStream_t stream)
{
  const float* uav  = (const float*)d_in[0];
  const float* task = (const float*)d_in[1];
  const float* uw0=(const float*)d_in[2];  const float* ub0=(const float*)d_in[3];
  const float* uw1=(const float*)d_in[4];  const float* ub1=(const float*)d_in[5];
  const float* uw2=(const float*)d_in[6];  const float* ub2=(const float*)d_in[7];
  const float* tw0=(const float*)d_in[8];  const float* tb0=(const float*)d_in[9];
  const float* tw1=(const float*)d_in[10]; const float* tb1=(const float*)d_in[11];
  const float* tw2=(const float*)d_in[12]; const float* tb2=(const float*)d_in[13];
  const float* headq=(const float*)d_in[14];
  const float* fw1=(const float*)d_in[15];
  const float* fb1=(const float*)d_in[16];
  const float* fw2=(const float*)d_in[17];
  const float* fb2=(const float*)d_in[18];

  float* ws  = (float*)d_ws;
  float* ueW = ws;                          // 1024*256 fp32 = 1 MB
  float* QhW = ws + 1024*256;               // 4*256 fp32 = 4 KB
  bf16*  Kg  = (bf16*)(ws + 1024*256 + 4*256); // 2048*256 bf16 = 1 MB

  float* out = (float*)d_out;

  hipLaunchKernelGGL(enc_kernel, dim3(769), dim3(128), 0, stream,
      uav, task, uw0,ub0,uw1,ub1,uw2,ub2, tw0,tb0,tw1,tb1,tw2,tb2, headq, fw1,
      ueW, Kg, QhW);
  hipLaunchKernelGGL(logits_kernel, dim3(U_/UTILE, H_, B_), dim3(256), 0, stream,
      ueW, QhW, Kg, fb1, fw2, fb2, out);
}

// Round 3
// 130.912 us; speedup vs baseline: 1.0850x; 1.0850x over previous
//
#include <hip/hip_runtime.h>
#include <hip/hip_bf16.h>

#define B_ 16
#define U_ 64
#define T_ 128
#define H_ 4
#define E_ 128
#define HID_ 256

typedef _Float16 half_t;
typedef _Float16 h2 __attribute__((ext_vector_type(2)));

__device__ __forceinline__ h2 u2h(unsigned u){ h2 r; __builtin_memcpy(&r, &u, 4); return r; }
__device__ __forceinline__ unsigned pkh(float a, float b){
  h2 r; r.x = (_Float16)a; r.y = (_Float16)b;
  unsigned u; __builtin_memcpy(&u, &r, 4); return u;
}

// ---------------- encoder kernel ----------------
// 128 threads/block, ENC_R=8 rows per block. Fuses 3-layer MLP + fw1 projection.
// Inputs fp32 (reference dtypes). K output stored fp16 (internal format).
#define ENC_R 8

__device__ __forceinline__ void layer128(const float (*in)[128], float (*out)[128],
    const float* __restrict__ W, const float* __restrict__ Bb, int j, bool do_relu)
{
  float a[ENC_R];
  float bb = Bb[j];
  #pragma unroll
  for (int r=0;r<ENC_R;r++) a[r]=bb;
  #pragma unroll
  for (int ic=0; ic<4; ic++){
    float w[32];
    #pragma unroll
    for (int i=0;i<32;i++) w[i]=W[(ic*32+i)*128 + j];
    #pragma unroll
    for (int r=0;r<ENC_R;r++){
      float s=0.f;
      #pragma unroll
      for (int i=0;i<32;i++) s = fmaf(in[r][ic*32+i], w[i], s);
      a[r]+=s;
    }
  }
  #pragma unroll
  for (int r=0;r<ENC_R;r++) out[r][j] = do_relu ? fmaxf(a[r],0.f) : a[r];
}

__global__ __launch_bounds__(128) void enc_kernel(
  const float* __restrict__ uav, const float* __restrict__ task,
  const float* __restrict__ uw0, const float* __restrict__ ub0,
  const float* __restrict__ uw1, const float* __restrict__ ub1,
  const float* __restrict__ uw2, const float* __restrict__ ub2,
  const float* __restrict__ tw0, const float* __restrict__ tb0,
  const float* __restrict__ tw1, const float* __restrict__ tb1,
  const float* __restrict__ tw2, const float* __restrict__ tb2,
  const float* __restrict__ headq, const float* __restrict__ fw1,
  float* __restrict__ ueW, half_t* __restrict__ Kg, float* __restrict__ QhW)
{
  __shared__ float X[ENC_R][32];
  __shared__ float Ha[ENC_R][128];
  __shared__ float Hb[ENC_R][128];
  const int j = threadIdx.x;
  const int blk = blockIdx.x;

  const float *w0=nullptr,*b0=nullptr,*w1=nullptr,*b1=nullptr,*w2=nullptr,*b2=nullptr,*xin=nullptr;
  const float* fwbase;
  float* outF = nullptr;
  half_t* outB = nullptr;
  bool only_last = false;
  int row0;

  if (blk < 128) {            // uav path: rows (b*U+u), output ueW fp32
    row0 = blk*ENC_R;
    xin = uav + row0*32;
    w0=uw0;b0=ub0;w1=uw1;b1=ub1;w2=uw2;b2=ub2;
    fwbase = fw1;             // fw1[:E]
    outF = ueW + row0*HID_;
  } else if (blk < 384) {     // task path: rows (b*T+t), output K fp16
    row0 = (blk-128)*ENC_R;
    xin = task + row0*32;
    w0=tw0;b0=tb0;w1=tw1;b1=tb1;w2=tw2;b2=tb2;
    fwbase = fw1 + 128*HID_;  // fw1[E:]
    outB = Kg + row0*HID_;
  } else {                    // head_q: only L3, 4 rows
    only_last = true;
    fwbase = fw1;
    outF = QhW;
  }

  if (!only_last) {
    for (int idx=j; idx<ENC_R*32; idx+=128){ int r=idx>>5, i=idx&31; X[r][i]=xin[idx]; }
    __syncthreads();
    // L0: 32 -> 128, relu
    {
      float w[32];
      #pragma unroll
      for (int i=0;i<32;i++) w[i]=w0[i*128 + j];
      float bb=b0[j];
      #pragma unroll
      for (int r=0;r<ENC_R;r++){
        float a=bb;
        #pragma unroll
        for (int i=0;i<32;i++) a = fmaf(X[r][i], w[i], a);
        Ha[r][j]=fmaxf(a,0.f);
      }
    }
    __syncthreads();
    layer128(Ha,Hb,w1,b1,j,true);    // L1 relu
    __syncthreads();
    layer128(Hb,Ha,w2,b2,j,false);   // L2 NO relu
    __syncthreads();
  } else {
    #pragma unroll
    for (int r=0;r<4;r++) Ha[r][j] = headq[r*128 + j];
    __syncthreads();
  }

  // L3: E(128) -> HID(256) with fw1 part; no bias (fb1 folded into logits base)
  #pragma unroll
  for (int o=0;o<2;o++){
    const int jo = o*128 + j;
    float a[ENC_R];
    #pragma unroll
    for (int r=0;r<ENC_R;r++) a[r]=0.f;
    #pragma unroll
    for (int ic=0; ic<4; ic++){
      float w[32];
      #pragma unroll
      for (int i=0;i<32;i++) w[i]=fwbase[(ic*32+i)*HID_ + jo];
      #pragma unroll
      for (int r=0;r<ENC_R;r++){
        float s=0.f;
        #pragma unroll
        for (int i=0;i<32;i++) s = fmaf(Ha[r][ic*32+i], w[i], s);
        a[r]+=s;
      }
    }
    if (!only_last) {
      if (outF) {
        #pragma unroll
        for (int r=0;r<ENC_R;r++) outF[r*HID_ + jo] = a[r];
      } else {
        #pragma unroll
        for (int r=0;r<ENC_R;r++) outB[r*HID_ + jo] = (half_t)a[r];
      }
    } else {
      #pragma unroll
      for (int r=0;r<4;r++) outF[r*HID_ + jo] = a[r];
    }
  }
}

// ---------------- logits kernel ----------------
// Block = (u-tile of 8, h, b), 256 threads = 4 waves, each wave owns 2 u-rows,
// lane owns t = stage*64 + lane. K staged in LDS as fp16 uint4[t][32] with
// rotation swizzle (c+t)&31: reads AND writes hit all 32 banks. base/w2 are
// wave-uniform b128 broadcasts. Inner math: v_pk_add_f16/v_pk_max_f16/v_dot2.
#define UTILE 8

__global__ __launch_bounds__(256) void logits_kernel(
  const float* __restrict__ ueW, const float* __restrict__ QhW,
  const half_t* __restrict__ Kg,
  const float* __restrict__ fb1, const float* __restrict__ fw2,
  const float* __restrict__ fb2, float* __restrict__ out)
{
  __shared__ uint4 Kl4[64*32];     // 32 KB: [t][rot(c)]
  __shared__ uint4 baseb[UTILE][32]; // 4 KB: fp16 pairs of ueW+QhW+fb1
  __shared__ uint4 w2b[32];        // 512 B: fp16 pairs of fw2

  const int tid = threadIdx.x;
  const int wv = tid >> 6;
  const int lane = tid & 63;
  const int b = blockIdx.z, h = blockIdx.y;
  const int u0 = blockIdx.x * UTILE;

  // ---- prep base (8 u-rows) and w2 in fp16 ----
  {
    const int u = tid >> 5;       // 0..7
    const int c = tid & 31;       // 0..31  (chunk of 8 d)
    const float4* ue4 = (const float4*)(ueW + (b*U_ + u0 + u)*HID_);
    const float4* q4  = (const float4*)(QhW + h*HID_);
    const float4* f4  = (const float4*)fb1;
    float4 a0 = ue4[2*c],   a1 = ue4[2*c+1];
    float4 b0 = q4[2*c],    b1 = q4[2*c+1];
    float4 c0 = f4[2*c],    c1 = f4[2*c+1];
    uint4 pv;
    pv.x = pkh(a0.x+b0.x+c0.x, a0.y+b0.y+c0.y);
    pv.y = pkh(a0.z+b0.z+c0.z, a0.w+b0.w+c0.w);
    pv.z = pkh(a1.x+b1.x+c1.x, a1.y+b1.y+c1.y);
    pv.w = pkh(a1.z+b1.z+c1.z, a1.w+b1.w+c1.w);
    baseb[u][c] = pv;
    if (tid < 32) {
      const float4* w4 = (const float4*)fw2;
      float4 w0 = w4[2*tid], w1 = w4[2*tid+1];
      uint4 wv4;
      wv4.x = pkh(w0.x, w0.y); wv4.y = pkh(w0.z, w0.w);
      wv4.z = pkh(w1.x, w1.y); wv4.w = pkh(w1.z, w1.w);
      w2b[tid] = wv4;
    }
  }
  const float fb2f = fb2[0];
  const uint4* Kgp = (const uint4*)(Kg + (size_t)b*T_*HID_);  // row t = 32 uint4

  const int r0 = wv*2;
  const h2 hz = (h2)((_Float16)0);

  for (int s=0; s<2; s++){
    const int t0 = s*64;
    if (s) __syncthreads();               // protect Kl reuse
    // ---- stage K[t0..t0+63] : coalesced global, rotated LDS write ----
    for (int i = tid; i < 64*32; i += 256){
      const int t = i >> 5, c = i & 31;
      Kl4[t*32 + ((c + t)&31)] = Kgp[(t0 + t)*32 + c];
    }
    __syncthreads();                      // Kl (and on s==0: baseb/w2b) ready
    // ---- compute: 2 u-rows, t = t0+lane ----
    const uint4* myrow = Kl4 + lane*32;
    float acc0 = 0.f, acc1 = 0.f;
    #pragma unroll
    for (int c=0; c<32; c++){
      const uint4 kv = myrow[(c + lane)&31];
      const uint4 w4 = w2b[c];
      const uint4 p0 = baseb[r0][c];
      const uint4 p1 = baseb[r0+1][c];
      h2 x;
      x = __builtin_elementwise_max(u2h(p0.x)+u2h(kv.x), hz);
      acc0 = __builtin_amdgcn_fdot2(x, u2h(w4.x), acc0, false);
      x = __builtin_elementwise_max(u2h(p0.y)+u2h(kv.y), hz);
      acc0 = __builtin_amdgcn_fdot2(x, u2h(w4.y), acc0, false);
      x = __builtin_elementwise_max(u2h(p0.z)+u2h(kv.z), hz);
      acc0 = __builtin_amdgcn_fdot2(x, u2h(w4.z), acc0, false);
      x = __builtin_elementwise_max(u2h(p0.w)+u2h(kv.w), hz);
      acc0 = __builtin_amdgcn_fdot2(x, u2h(w4.w), acc0, false);
      x = __builtin_elementwise_max(u2h(p1.x)+u2h(kv.x), hz);
      acc1 = __builtin_amdgcn_fdot2(x, u2h(w4.x), acc1, false);
      x = __builtin_elementwise_max(u2h(p1.y)+u2h(kv.y), hz);
      acc1 = __builtin_amdgcn_fdot2(x, u2h(w4.y), acc1, false);
      x = __builtin_elementwise_max(u2h(p1.z)+u2h(kv.z), hz);
      acc1 = __builtin_amdgcn_fdot2(x, u2h(w4.z), acc1, false);
      x = __builtin_elementwise_max(u2h(p1.w)+u2h(kv.w), hz);
      acc1 = __builtin_amdgcn_fdot2(x, u2h(w4.w), acc1, false);
    }
    const int t = t0 + lane;
    out[((b*H_ + h)*U_ + (u0 + r0    ))*T_ + t] = acc0 + fb2f;
    out[((b*H_ + h)*U_ + (u0 + r0 + 1))*T_ + t] = acc1 + fb2f;
  }
}

extern "C" void kernel_launch(void* const* d_in, const int* in_sizes, int n_in,
                              void* d_out, int out_size, void* d_ws, size_t ws_size,
                              hipStream_t stream)
{
  const float* uav  = (const float*)d_in[0];
  const float* task = (const float*)d_in[1];
  const float* uw0=(const float*)d_in[2];  const float* ub0=(const float*)d_in[3];
  const float* uw1=(const float*)d_in[4];  const float* ub1=(const float*)d_in[5];
  const float* uw2=(const float*)d_in[6];  const float* ub2=(const float*)d_in[7];
  const float* tw0=(const float*)d_in[8];  const float* tb0=(const float*)d_in[9];
  const float* tw1=(const float*)d_in[10]; const float* tb1=(const float*)d_in[11];
  const float* tw2=(const float*)d_in[12]; const float* tb2=(const float*)d_in[13];
  const float* headq=(const float*)d_in[14];
  const float* fw1=(const float*)d_in[15];
  const float* fb1=(const float*)d_in[16];
  const float* fw2=(const float*)d_in[17];
  const float* fb2=(const float*)d_in[18];

  float* ws  = (float*)d_ws;
  float* ueW = ws;                            // 1024*256 fp32 = 1 MB
  float* QhW = ws + 1024*256;                 // 4*256 fp32 = 4 KB
  half_t* Kg = (half_t*)(ws + 1024*256 + 4*256); // 2048*256 fp16 = 1 MB

  float* out = (float*)d_out;

  hipLaunchKernelGGL(enc_kernel, dim3(385), dim3(128), 0, stream,
      uav, task, uw0,ub0,uw1,ub1,uw2,ub2, tw0,tb0,tw1,tb1,tw2,tb2, headq, fw1,
      ueW, Kg, QhW);
  hipLaunchKernelGGL(logits_kernel, dim3(U_/UTILE, H_, B_), dim3(256), 0, stream,
      ueW, QhW, Kg, fb1, fw2, fb2, out);
}

// Round 4
// 116.130 us; speedup vs baseline: 1.2231x; 1.1273x over previous
//
#include <hip/hip_runtime.h>
#include <hip/hip_bf16.h>

#define B_ 16
#define U_ 64
#define T_ 128
#define H_ 4
#define E_ 128
#define HID_ 256

typedef _Float16 half_t;
typedef _Float16 h2 __attribute__((ext_vector_type(2)));
typedef _Float16 f16x8 __attribute__((ext_vector_type(8)));
typedef float f32x4 __attribute__((ext_vector_type(4)));

__device__ __forceinline__ h2 u2h(unsigned u){ h2 r; __builtin_memcpy(&r, &u, 4); return r; }
__device__ __forceinline__ unsigned pkh(float a, float b){
  h2 r; r.x = (_Float16)a; r.y = (_Float16)b;
  unsigned u; __builtin_memcpy(&u, &r, 4); return u;
}

// ---------------- prep kernel ----------------
// Blocks 0..33: transpose-convert fp32 weights -> fp16 Wt[n][k] (32k x 128n tiles).
// Block 34: QhW = head_q @ fw1[:E]  (4x256 fp32).
__global__ __launch_bounds__(256) void prep_kernel(
  const float* __restrict__ uw0, const float* __restrict__ uw1, const float* __restrict__ uw2,
  const float* __restrict__ tw0, const float* __restrict__ tw1, const float* __restrict__ tw2,
  const float* __restrict__ fw1, const float* __restrict__ headq,
  half_t* __restrict__ u0t, half_t* __restrict__ u1t, half_t* __restrict__ u2t,
  half_t* __restrict__ t0t, half_t* __restrict__ t1t, half_t* __restrict__ t2t,
  half_t* __restrict__ f1at, half_t* __restrict__ f1bt, float* __restrict__ QhW)
{
  const int tid = threadIdx.x;
  const int b = blockIdx.x;
  if (b == 34) {                       // QhW
    const int n = tid;
    float acc[4] = {0.f,0.f,0.f,0.f};
    for (int e=0;e<128;e++){
      float w = fw1[e*256 + n];        // coalesced across tid
      #pragma unroll
      for (int h=0;h<4;h++) acc[h] = fmaf(headq[h*128+e], w, acc[h]);
    }
    #pragma unroll
    for (int h=0;h<4;h++) QhW[h*256+n] = acc[h];
    return;
  }
  const float* src; int srcStride, row0, col0; half_t* dst; int dstStride, nOff, kOff;
  if (b < 9) {
    if (b==0){ src=uw0; row0=0;        dst=u0t; dstStride=32;  kOff=0; }
    else if (b<5){ src=uw1; row0=(b-1)*32; dst=u1t; dstStride=128; kOff=row0; }
    else { src=uw2; row0=(b-5)*32; dst=u2t; dstStride=128; kOff=row0; }
    srcStride=128; col0=0; nOff=0;
  } else if (b < 18) {
    int bb=b-9;
    if (bb==0){ src=tw0; row0=0;        dst=t0t; dstStride=32;  kOff=0; }
    else if (bb<5){ src=tw1; row0=(bb-1)*32; dst=t1t; dstStride=128; kOff=row0; }
    else { src=tw2; row0=(bb-5)*32; dst=t2t; dstStride=128; kOff=row0; }
    srcStride=128; col0=0; nOff=0;
  } else if (b < 26) {
    int idx=b-18, kc=idx&3, nc=idx>>2;
    src=fw1; srcStride=256; row0=kc*32; col0=nc*128;
    dst=f1at; dstStride=128; kOff=kc*32; nOff=col0;
  } else {
    int idx=b-26, kc=idx&3, nc=idx>>2;
    src=fw1; srcStride=256; row0=128+kc*32; col0=nc*128;
    dst=f1bt; dstStride=128; kOff=kc*32; nOff=col0;
  }
  __shared__ half_t tl[128][33];
  #pragma unroll
  for (int i=0;i<16;i++){ int idx=i*256+tid; int k=idx>>7, n=idx&127;
    tl[n][k] = (half_t)src[(row0+k)*srcStride + col0 + n]; }
  __syncthreads();
  #pragma unroll
  for (int i=0;i<16;i++){ int idx=i*256+tid; int n=idx>>5, k=idx&31;
    dst[(nOff+n)*dstStride + kOff + k] = tl[n][k]; }
}

// ---------------- MFMA encoder ----------------
// 48 blocks x 256 thr; block = 64 rows (uav: blk<16, task: blk>=16).
// Weights are the A-operand (Wt[n][k] tiles), activations the B-operand:
// D row = quad*4+reg = 4 consecutive OUT features -> b64 epilogue writes.
// LDS pitch 136 halves: 16-B aligned frags, row bank-shift 4 -> 2-way (free).
#define PITCH 136

template<int KTILES, int NTILES, bool RELU>
__device__ __forceinline__ void layer_mfma(const half_t* __restrict__ in,
    const half_t* __restrict__ W, const float* __restrict__ bias,
    half_t* __restrict__ out, int m0, int quad, int l16)
{
  f16x8 bfrag[KTILES];
  const half_t* ip = in + (m0+l16)*PITCH + quad*8;
  #pragma unroll
  for (int kk=0;kk<KTILES;kk++) bfrag[kk] = *(const f16x8*)(ip + kk*32);
  #pragma unroll
  for (int nt=0; nt<NTILES; nt++){
    f32x4 acc = {0.f,0.f,0.f,0.f};
    const half_t* wp = W + (nt*16+l16)*PITCH + quad*8;
    #pragma unroll
    for (int kk=0;kk<KTILES;kk++){
      f16x8 a = *(const f16x8*)(wp + kk*32);
      acc = __builtin_amdgcn_mfma_f32_16x16x32_f16(a, bfrag[kk], acc, 0, 0, 0);
    }
    const int n0 = nt*16 + quad*4;
    const float4 bv = *(const float4*)(bias + n0);
    float bvr[4] = {bv.x, bv.y, bv.z, bv.w};
    union { half_t h[4]; uint2 u; } pv;
    #pragma unroll
    for (int r=0;r<4;r++){
      float x = acc[r] + bvr[r];
      if (RELU) x = fmaxf(x, 0.f);
      pv.h[r] = (half_t)x;
    }
    *(uint2*)(out + (m0+l16)*PITCH + n0) = pv.u;
  }
}

__global__ __launch_bounds__(256) void enc_mfma(
  const float* __restrict__ uav, const float* __restrict__ task,
  const float* __restrict__ ub0, const float* __restrict__ ub1, const float* __restrict__ ub2,
  const float* __restrict__ tb0, const float* __restrict__ tb1, const float* __restrict__ tb2,
  const half_t* __restrict__ u0t, const half_t* __restrict__ u1t, const half_t* __restrict__ u2t,
  const half_t* __restrict__ t0t, const half_t* __restrict__ t1t, const half_t* __restrict__ t2t,
  const half_t* __restrict__ f1at, const half_t* __restrict__ f1bt,
  float* __restrict__ ueW, half_t* __restrict__ Kg)
{
  __shared__ half_t Wb[256*PITCH];     // 69632 B
  __shared__ half_t actA[64*PITCH];    // 17408 B
  __shared__ half_t actB[64*PITCH];    // 17408 B
  const int tid = threadIdx.x, lane = tid&63, wv = tid>>6;
  const int quad = lane>>4, l16 = lane&15;
  const int m0 = wv*16;
  const bool isU = blockIdx.x < 16;
  const int rows0 = (isU ? blockIdx.x : blockIdx.x - 16) * 64;
  const float* Xsrc = (isU ? uav : task) + rows0*32;
  const half_t* W0 = isU ? u0t : t0t;
  const half_t* W1 = isU ? u1t : t1t;
  const half_t* W2 = isU ? u2t : t2t;
  const half_t* W3 = isU ? f1at : f1bt;
  const float* bias0 = isU ? ub0 : tb0;
  const float* bias1 = isU ? ub1 : tb1;
  const float* bias2 = isU ? ub2 : tb2;

  // stage X (64x32 fp32 -> fp16)
  {
    const int r = tid>>2, q = tid&3;
    const float4 v0 = *(const float4*)(Xsrc + r*32 + q*8);
    const float4 v1 = *(const float4*)(Xsrc + r*32 + q*8 + 4);
    half_t* d = actA + r*PITCH + q*8;
    d[0]=(half_t)v0.x; d[1]=(half_t)v0.y; d[2]=(half_t)v0.z; d[3]=(half_t)v0.w;
    d[4]=(half_t)v1.x; d[5]=(half_t)v1.y; d[6]=(half_t)v1.z; d[7]=(half_t)v1.w;
  }
  // stage W0 (128n x 32k)
  {
    const uint4* s = (const uint4*)W0;
    #pragma unroll
    for (int i=0;i<2;i++){ int idx=i*256+tid; int n=idx>>2, kc=idx&3;
      *(uint4*)(Wb + n*PITCH + kc*8) = s[idx]; }
  }
  __syncthreads();
  layer_mfma<1,8,true >(actA, Wb, bias0, actB, m0, quad, l16);
  __syncthreads();
  { const uint4* s = (const uint4*)W1;
    #pragma unroll
    for (int i=0;i<8;i++){ int idx=i*256+tid; int n=idx>>4, kc=idx&15;
      *(uint4*)(Wb + n*PITCH + kc*8) = s[idx]; } }
  __syncthreads();
  layer_mfma<4,8,true >(actB, Wb, bias1, actA, m0, quad, l16);
  __syncthreads();
  { const uint4* s = (const uint4*)W2;
    #pragma unroll
    for (int i=0;i<8;i++){ int idx=i*256+tid; int n=idx>>4, kc=idx&15;
      *(uint4*)(Wb + n*PITCH + kc*8) = s[idx]; } }
  __syncthreads();
  layer_mfma<4,8,false>(actA, Wb, bias2, actB, m0, quad, l16);   // L2: linear
  __syncthreads();
  { const uint4* s = (const uint4*)W3;                            // 256n x 128k
    #pragma unroll
    for (int i=0;i<16;i++){ int idx=i*256+tid; int n=idx>>4, kc=idx&15;
      *(uint4*)(Wb + n*PITCH + kc*8) = s[idx]; } }
  __syncthreads();
  // L3: K=128 -> N=256, no bias/relu, straight to global
  {
    f16x8 bfrag[4];
    const half_t* ip = actB + (m0+l16)*PITCH + quad*8;
    #pragma unroll
    for (int kk=0;kk<4;kk++) bfrag[kk] = *(const f16x8*)(ip + kk*32);
    const int grow = rows0 + m0 + l16;
    #pragma unroll
    for (int nt=0; nt<16; nt++){
      f32x4 acc = {0.f,0.f,0.f,0.f};
      const half_t* wp = Wb + (nt*16+l16)*PITCH + quad*8;
      #pragma unroll
      for (int kk=0;kk<4;kk++){
        f16x8 a = *(const f16x8*)(wp + kk*32);
        acc = __builtin_amdgcn_mfma_f32_16x16x32_f16(a, bfrag[kk], acc, 0, 0, 0);
      }
      const int n0 = nt*16 + quad*4;
      if (isU){
        *(float4*)(ueW + grow*256 + n0) = make_float4(acc[0],acc[1],acc[2],acc[3]);
      } else {
        union { half_t h[4]; uint2 u; } pv;
        pv.h[0]=(half_t)acc[0]; pv.h[1]=(half_t)acc[1];
        pv.h[2]=(half_t)acc[2]; pv.h[3]=(half_t)acc[3];
        *(uint2*)(Kg + grow*256 + n0) = pv.u;
      }
    }
  }
}

// ---------------- logits kernel (unchanged from round 3) ----------------
#define UTILE 8

__global__ __launch_bounds__(256) void logits_kernel(
  const float* __restrict__ ueW, const float* __restrict__ QhW,
  const half_t* __restrict__ Kg,
  const float* __restrict__ fb1, const float* __restrict__ fw2,
  const float* __restrict__ fb2, float* __restrict__ out)
{
  __shared__ uint4 Kl4[64*32];
  __shared__ uint4 baseb[UTILE][32];
  __shared__ uint4 w2b[32];

  const int tid = threadIdx.x;
  const int wv = tid >> 6;
  const int lane = tid & 63;
  const int b = blockIdx.z, h = blockIdx.y;
  const int u0 = blockIdx.x * UTILE;

  {
    const int u = tid >> 5;
    const int c = tid & 31;
    const float4* ue4 = (const float4*)(ueW + (b*U_ + u0 + u)*HID_);
    const float4* q4  = (const float4*)(QhW + h*HID_);
    const float4* f4  = (const float4*)fb1;
    float4 a0 = ue4[2*c],   a1 = ue4[2*c+1];
    float4 b0 = q4[2*c],    b1 = q4[2*c+1];
    float4 c0 = f4[2*c],    c1 = f4[2*c+1];
    uint4 pv;
    pv.x = pkh(a0.x+b0.x+c0.x, a0.y+b0.y+c0.y);
    pv.y = pkh(a0.z+b0.z+c0.z, a0.w+b0.w+c0.w);
    pv.z = pkh(a1.x+b1.x+c1.x, a1.y+b1.y+c1.y);
    pv.w = pkh(a1.z+b1.z+c1.z, a1.w+b1.w+c1.w);
    baseb[u][c] = pv;
    if (tid < 32) {
      const float4* w4 = (const float4*)fw2;
      float4 w0 = w4[2*tid], w1 = w4[2*tid+1];
      uint4 wv4;
      wv4.x = pkh(w0.x, w0.y); wv4.y = pkh(w0.z, w0.w);
      wv4.z = pkh(w1.x, w1.y); wv4.w = pkh(w1.z, w1.w);
      w2b[tid] = wv4;
    }
  }
  const float fb2f = fb2[0];
  const uint4* Kgp = (const uint4*)(Kg + (size_t)b*T_*HID_);

  const int r0 = wv*2;
  const h2 hz = (h2)((_Float16)0);

  for (int s=0; s<2; s++){
    const int t0 = s*64;
    if (s) __syncthreads();
    for (int i = tid; i < 64*32; i += 256){
      const int t = i >> 5, c = i & 31;
      Kl4[t*32 + ((c + t)&31)] = Kgp[(t0 + t)*32 + c];
    }
    __syncthreads();
    const uint4* myrow = Kl4 + lane*32;
    float acc0 = 0.f, acc1 = 0.f;
    #pragma unroll
    for (int c=0; c<32; c++){
      const uint4 kv = myrow[(c + lane)&31];
      const uint4 w4 = w2b[c];
      const uint4 p0 = baseb[r0][c];
      const uint4 p1 = baseb[r0+1][c];
      h2 x;
      x = __builtin_elementwise_max(u2h(p0.x)+u2h(kv.x), hz);
      acc0 = __builtin_amdgcn_fdot2(x, u2h(w4.x), acc0, false);
      x = __builtin_elementwise_max(u2h(p0.y)+u2h(kv.y), hz);
      acc0 = __builtin_amdgcn_fdot2(x, u2h(w4.y), acc0, false);
      x = __builtin_elementwise_max(u2h(p0.z)+u2h(kv.z), hz);
      acc0 = __builtin_amdgcn_fdot2(x, u2h(w4.z), acc0, false);
      x = __builtin_elementwise_max(u2h(p0.w)+u2h(kv.w), hz);
      acc0 = __builtin_amdgcn_fdot2(x, u2h(w4.w), acc0, false);
      x = __builtin_elementwise_max(u2h(p1.x)+u2h(kv.x), hz);
      acc1 = __builtin_amdgcn_fdot2(x, u2h(w4.x), acc1, false);
      x = __builtin_elementwise_max(u2h(p1.y)+u2h(kv.y), hz);
      acc1 = __builtin_amdgcn_fdot2(x, u2h(w4.y), acc1, false);
      x = __builtin_elementwise_max(u2h(p1.z)+u2h(kv.z), hz);
      acc1 = __builtin_amdgcn_fdot2(x, u2h(w4.z), acc1, false);
      x = __builtin_elementwise_max(u2h(p1.w)+u2h(kv.w), hz);
      acc1 = __builtin_amdgcn_fdot2(x, u2h(w4.w), acc1, false);
    }
    const int t = t0 + lane;
    out[((b*H_ + h)*U_ + (u0 + r0    ))*T_ + t] = acc0 + fb2f;
    out[((b*H_ + h)*U_ + (u0 + r0 + 1))*T_ + t] = acc1 + fb2f;
  }
}

extern "C" void kernel_launch(void* const* d_in, const int* in_sizes, int n_in,
                              void* d_out, int out_size, void* d_ws, size_t ws_size,
                              hipStream_t stream)
{
  const float* uav  = (const float*)d_in[0];
  const float* task = (const float*)d_in[1];
  const float* uw0=(const float*)d_in[2];  const float* ub0=(const float*)d_in[3];
  const float* uw1=(const float*)d_in[4];  const float* ub1=(const float*)d_in[5];
  const float* uw2=(const float*)d_in[6];  const float* ub2=(const float*)d_in[7];
  const float* tw0=(const float*)d_in[8];  const float* tb0=(const float*)d_in[9];
  const float* tw1=(const float*)d_in[10]; const float* tb1=(const float*)d_in[11];
  const float* tw2=(const float*)d_in[12]; const float* tb2=(const float*)d_in[13];
  const float* headq=(const float*)d_in[14];
  const float* fw1=(const float*)d_in[15];
  const float* fb1=(const float*)d_in[16];
  const float* fw2=(const float*)d_in[17];
  const float* fb2=(const float*)d_in[18];

  float* ueW = (float*)d_ws;                 // 262144 floats (1 MB)
  float* QhW = ueW + 262144;                 // 1024 floats
  half_t* hb = (half_t*)(QhW + 1024);
  half_t* u0t  = hb;                         // 4096
  half_t* u1t  = hb + 4096;                  // 16384
  half_t* u2t  = hb + 20480;                 // 16384
  half_t* t0t  = hb + 36864;                 // 4096
  half_t* t1t  = hb + 40960;                 // 16384
  half_t* t2t  = hb + 57344;                 // 16384
  half_t* f1at = hb + 73728;                 // 32768
  half_t* f1bt = hb + 106496;                // 32768
  half_t* Kg   = hb + 139264;                // 524288

  float* out = (float*)d_out;

  hipLaunchKernelGGL(prep_kernel, dim3(35), dim3(256), 0, stream,
      uw0, uw1, uw2, tw0, tw1, tw2, fw1, headq,
      u0t, u1t, u2t, t0t, t1t, t2t, f1at, f1bt, QhW);
  hipLaunchKernelGGL(enc_mfma, dim3(48), dim3(256), 0, stream,
      uav, task, ub0, ub1, ub2, tb0, tb1, tb2,
      u0t, u1t, u2t, t0t, t1t, t2t, f1at, f1bt, ueW, Kg);
  hipLaunchKernelGGL(logits_kernel, dim3(U_/UTILE, H_, B_), dim3(256), 0, stream,
      ueW, QhW, Kg, fb1, fw2, fb2, out);
}

// Round 5
// 113.279 us; speedup vs baseline: 1.2539x; 1.0252x over previous
//
#include <hip/hip_runtime.h>
#include <hip/hip_bf16.h>

#define B_ 16
#define U_ 64
#define T_ 128
#define H_ 4
#define E_ 128
#define HID_ 256

typedef _Float16 half_t;
typedef _Float16 h2 __attribute__((ext_vector_type(2)));
typedef _Float16 f16x8 __attribute__((ext_vector_type(8)));
typedef float f32x4 __attribute__((ext_vector_type(4)));

__device__ __forceinline__ h2 u2h(unsigned u){ h2 r; __builtin_memcpy(&r, &u, 4); return r; }
__device__ __forceinline__ unsigned pkh(float a, float b){
  h2 r; r.x = (_Float16)a; r.y = (_Float16)b;
  unsigned u; __builtin_memcpy(&u, &r, 4); return u;
}

#define PITCH 136   // halves; 272 B row stride -> b128 frags 16B-aligned, conflict-free
#define PITCH0 40   // W0 buffer (K=32): 80 B stride

// Transpose-convert: src fp32 (k-major, row len SRCN) -> dst fp16 Wt[n][k].
// Thread handles rows n, k-chunks kc0..kc0+KC-1 (8 k each): 8 strided coalesced
// loads -> pack -> one b128 LDS write.
template<int KC, int SRCN>
__device__ __forceinline__ void stageW(const float* __restrict__ src,
    half_t* __restrict__ dst, int n, int kc0, int pitch)
{
  #pragma unroll
  for (int f=0; f<KC; f++){
    const int kc = kc0 + f;
    float v[8];
    #pragma unroll
    for (int j=0;j<8;j++) v[j] = src[(kc*8+j)*SRCN + n];
    union{ half_t h[8]; uint4 u; } p;
    #pragma unroll
    for (int j=0;j<8;j++) p.h[j] = (half_t)v[j];
    *(uint4*)(dst + n*pitch + kc*8) = p.u;
  }
}

// D row (quad*4+reg) = 4 consecutive OUT features; b64 epilogue (2-way free).
template<int KTILES, int NTILES, int WPITCH, bool RELU>
__device__ __forceinline__ void layer_mfma(const half_t* __restrict__ in,
    const half_t* __restrict__ W, const float* __restrict__ bias,
    half_t* __restrict__ out, int m0, int quad, int l16)
{
  f16x8 bfrag[KTILES];
  const half_t* ip = in + (m0+l16)*PITCH + quad*8;
  #pragma unroll
  for (int kk=0;kk<KTILES;kk++) bfrag[kk] = *(const f16x8*)(ip + kk*32);
  #pragma unroll
  for (int nt=0; nt<NTILES; nt++){
    f32x4 acc = {0.f,0.f,0.f,0.f};
    const half_t* wp = W + (nt*16+l16)*WPITCH + quad*8;
    #pragma unroll
    for (int kk=0;kk<KTILES;kk++){
      f16x8 a = *(const f16x8*)(wp + kk*32);
      acc = __builtin_amdgcn_mfma_f32_16x16x32_f16(a, bfrag[kk], acc, 0, 0, 0);
    }
    const int n0 = nt*16 + quad*4;
    const float4 bv = *(const float4*)(bias + n0);
    float bvr[4] = {bv.x, bv.y, bv.z, bv.w};
    union { half_t h[4]; uint2 u; } pv;
    #pragma unroll
    for (int r=0;r<4;r++){
      float x = acc[r] + bvr[r];
      if (RELU) x = fmaxf(x, 0.f);
      pv.h[r] = (half_t)x;
    }
    *(uint2*)(out + (m0+l16)*PITCH + n0) = pv.u;
  }
}

// ---------------- fused encoder: inline weight transpose + 4 MFMA layers ----
// grid 49: blk 0..15 uav rows, 16..47 task rows, 48 = QhW (= head_q @ fw1[:E]).
__global__ __launch_bounds__(256) void enc_mfma(
  const float* __restrict__ uav, const float* __restrict__ task,
  const float* __restrict__ uw0, const float* __restrict__ ub0,
  const float* __restrict__ uw1, const float* __restrict__ ub1,
  const float* __restrict__ uw2, const float* __restrict__ ub2,
  const float* __restrict__ tw0, const float* __restrict__ tb0,
  const float* __restrict__ tw1, const float* __restrict__ tb1,
  const float* __restrict__ tw2, const float* __restrict__ tb2,
  const float* __restrict__ headq, const float* __restrict__ fw1,
  float* __restrict__ ueW, half_t* __restrict__ Kg, float* __restrict__ QhW)
{
  __shared__ half_t W0b[128*PITCH0];   // 10240 B
  __shared__ half_t Wb[256*PITCH];     // 69632 B  (lo = rows 0..127, hi = 128..255)
  __shared__ half_t actA[64*PITCH];    // 17408 B
  __shared__ half_t actB[64*PITCH];    // 17408 B
  const int tid = threadIdx.x;

  if (blockIdx.x == 48) {              // QhW: 4x256 = head_q @ fw1[:128]
    const int n = tid;
    float acc[4] = {0.f,0.f,0.f,0.f};
    for (int e=0;e<128;e++){
      float w = fw1[e*256 + n];        // coalesced across tid
      #pragma unroll
      for (int h=0;h<4;h++) acc[h] = fmaf(headq[h*128+e], w, acc[h]);
    }
    #pragma unroll
    for (int h=0;h<4;h++) QhW[h*256+n] = acc[h];
    return;
  }

  const int lane = tid&63, wv = tid>>6;
  const int quad = lane>>4, l16 = lane&15;
  const int m0 = wv*16;
  const bool isU = blockIdx.x < 16;
  const int rows0 = (isU ? blockIdx.x : blockIdx.x - 16) * 64;
  const float* Xsrc = (isU ? uav : task) + rows0*32;
  const float* W0 = isU ? uw0 : tw0;
  const float* W1 = isU ? uw1 : tw1;
  const float* W2 = isU ? uw2 : tw2;
  const float* W3 = fw1 + (isU ? 0 : 128*HID_);
  const float* bias0 = isU ? ub0 : tb0;
  const float* bias1 = isU ? ub1 : tb1;
  const float* bias2 = isU ? ub2 : tb2;

  const int tn = tid & 127, th = tid >> 7;   // transpose thread mapping

  // ---- stage X + W0 + W1 + W2 (all loads independent, issued together) ----
  {
    const int r = tid>>2, q = tid&3;
    const float4 v0 = *(const float4*)(Xsrc + r*32 + q*8);
    const float4 v1 = *(const float4*)(Xsrc + r*32 + q*8 + 4);
    union{ half_t h[8]; uint4 u; } p;
    p.h[0]=(half_t)v0.x; p.h[1]=(half_t)v0.y; p.h[2]=(half_t)v0.z; p.h[3]=(half_t)v0.w;
    p.h[4]=(half_t)v1.x; p.h[5]=(half_t)v1.y; p.h[6]=(half_t)v1.z; p.h[7]=(half_t)v1.w;
    *(uint4*)(actA + r*PITCH + q*8) = p.u;
  }
  stageW<2,128>(W0, W0b, tn, th*2, PITCH0);          // 32k x 128n
  stageW<8,128>(W1, Wb,            tn, th*8, PITCH); // 128x128 -> rows 0..127
  stageW<8,128>(W2, Wb + 128*PITCH,tn, th*8, PITCH); // 128x128 -> rows 128..255
  __syncthreads();

  // activations are wave-private (wave w owns rows m0..m0+15) -> no barriers
  layer_mfma<1,8,PITCH0,true >(actA, W0b,          bias0, actB, m0, quad, l16);
  layer_mfma<4,8,PITCH, true >(actB, Wb,           bias1, actA, m0, quad, l16);
  __syncthreads();                       // all waves done reading Wb lo (W1)
  stageW<8,256>(W3, Wb, tn, th*8, PITCH);            // W3 rows 0..127 -> Wb lo
  layer_mfma<4,8,PITCH, false>(actA, Wb+128*PITCH, bias2, actB, m0, quad, l16);
  __syncthreads();                       // Wb hi (W2) free, W3lo written
  stageW<8,256>(W3, Wb, 128 + tn, th*8, PITCH);      // W3 rows 128..255 -> Wb hi
  __syncthreads();

  // L3: K=128 -> N=256, no bias/relu, straight to global
  {
    f16x8 bfrag[4];
    const half_t* ip = actB + (m0+l16)*PITCH + quad*8;
    #pragma unroll
    for (int kk=0;kk<4;kk++) bfrag[kk] = *(const f16x8*)(ip + kk*32);
    const int grow = rows0 + m0 + l16;
    #pragma unroll
    for (int nt=0; nt<16; nt++){
      f32x4 acc = {0.f,0.f,0.f,0.f};
      const half_t* wp = Wb + (nt*16+l16)*PITCH + quad*8;
      #pragma unroll
      for (int kk=0;kk<4;kk++){
        f16x8 a = *(const f16x8*)(wp + kk*32);
        acc = __builtin_amdgcn_mfma_f32_16x16x32_f16(a, bfrag[kk], acc, 0, 0, 0);
      }
      const int n0 = nt*16 + quad*4;
      if (isU){
        *(float4*)(ueW + grow*256 + n0) = make_float4(acc[0],acc[1],acc[2],acc[3]);
      } else {
        union { half_t h[4]; uint2 u; } pv;
        pv.h[0]=(half_t)acc[0]; pv.h[1]=(half_t)acc[1];
        pv.h[2]=(half_t)acc[2]; pv.h[3]=(half_t)acc[3];
        *(uint2*)(Kg + grow*256 + n0) = pv.u;
      }
    }
  }
}

// ---------------- logits kernel ----------------
// Block = (u-tile of 8, h, b), 256 thr. All 128 t staged once (64 KB, rotation
// swizzle). Wave = (row-quad, t-half): 4 u-rows x 64 t -> 6 LDS reads per
// 48 VALU. Single barrier.
#define UTILE 8

__global__ __launch_bounds__(256) void logits_kernel(
  const float* __restrict__ ueW, const float* __restrict__ QhW,
  const half_t* __restrict__ Kg,
  const float* __restrict__ fb1, const float* __restrict__ fw2,
  const float* __restrict__ fb2, float* __restrict__ out)
{
  __shared__ uint4 Kl4[128*32];      // 64 KB: [t][(c+t)&31]
  __shared__ uint4 baseb[UTILE][32]; // fp16 pairs of ueW+QhW+fb1
  __shared__ uint4 w2b[32];          // fp16 pairs of fw2

  const int tid = threadIdx.x;
  const int b = blockIdx.z, h = blockIdx.y;
  const int u0 = blockIdx.x * UTILE;

  // ---- base rows + w2 in fp16 ----
  {
    const int u = tid >> 5;
    const int c = tid & 31;
    const float4* ue4 = (const float4*)(ueW + (b*U_ + u0 + u)*HID_);
    const float4* q4  = (const float4*)(QhW + h*HID_);
    const float4* f4  = (const float4*)fb1;
    float4 a0 = ue4[2*c],   a1 = ue4[2*c+1];
    float4 b0 = q4[2*c],    b1 = q4[2*c+1];
    float4 c0 = f4[2*c],    c1 = f4[2*c+1];
    uint4 pv;
    pv.x = pkh(a0.x+b0.x+c0.x, a0.y+b0.y+c0.y);
    pv.y = pkh(a0.z+b0.z+c0.z, a0.w+b0.w+c0.w);
    pv.z = pkh(a1.x+b1.x+c1.x, a1.y+b1.y+c1.y);
    pv.w = pkh(a1.z+b1.z+c1.z, a1.w+b1.w+c1.w);
    baseb[u][c] = pv;
    if (tid < 32) {
      const float4* w4 = (const float4*)fw2;
      float4 w0 = w4[2*tid], w1 = w4[2*tid+1];
      uint4 wv4;
      wv4.x = pkh(w0.x, w0.y); wv4.y = pkh(w0.z, w0.w);
      wv4.z = pkh(w1.x, w1.y); wv4.w = pkh(w1.z, w1.w);
      w2b[tid] = wv4;
    }
  }
  // ---- stage all 128 t rows of K ----
  const uint4* Kgp = (const uint4*)(Kg + (size_t)b*T_*HID_);
  #pragma unroll
  for (int i = tid; i < 128*32; i += 256){
    const int t = i >> 5, c = i & 31;
    Kl4[t*32 + ((c + t)&31)] = Kgp[t*32 + c];
  }
  __syncthreads();

  const int wv = tid >> 6, lane = tid & 63;
  const int r0 = (wv & 1) * 4;          // row quad
  const int t  = (wv >> 1) * 64 + lane; // t owned by this lane
  const float fb2f = fb2[0];
  const uint4* myrow = Kl4 + t*32;
  const h2 hz = (h2)((_Float16)0);

  float acc[4] = {0.f,0.f,0.f,0.f};
  #pragma unroll
  for (int c=0; c<32; c++){
    const uint4 kv = myrow[(c + t)&31];
    const uint4 w4 = w2b[c];
    #pragma unroll
    for (int r=0; r<4; r++){
      const uint4 p = baseb[r0+r][c];
      h2 x;
      x = __builtin_elementwise_max(u2h(p.x)+u2h(kv.x), hz);
      acc[r] = __builtin_amdgcn_fdot2(x, u2h(w4.x), acc[r], false);
      x = __builtin_elementwise_max(u2h(p.y)+u2h(kv.y), hz);
      acc[r] = __builtin_amdgcn_fdot2(x, u2h(w4.y), acc[r], false);
      x = __builtin_elementwise_max(u2h(p.z)+u2h(kv.z), hz);
      acc[r] = __builtin_amdgcn_fdot2(x, u2h(w4.z), acc[r], false);
      x = __builtin_elementwise_max(u2h(p.w)+u2h(kv.w), hz);
      acc[r] = __builtin_amdgcn_fdot2(x, u2h(w4.w), acc[r], false);
    }
  }
  #pragma unroll
  for (int r=0; r<4; r++)
    out[((b*H_ + h)*U_ + (u0 + r0 + r))*T_ + t] = acc[r] + fb2f;
}

extern "C" void kernel_launch(void* const* d_in, const int* in_sizes, int n_in,
                              void* d_out, int out_size, void* d_ws, size_t ws_size,
                              hipStream_t stream)
{
  const float* uav  = (const float*)d_in[0];
  const float* task = (const float*)d_in[1];
  const float* uw0=(const float*)d_in[2];  const float* ub0=(const float*)d_in[3];
  const float* uw1=(const float*)d_in[4];  const float* ub1=(const float*)d_in[5];
  const float* uw2=(const float*)d_in[6];  const float* ub2=(const float*)d_in[7];
  const float* tw0=(const float*)d_in[8];  const float* tb0=(const float*)d_in[9];
  const float* tw1=(const float*)d_in[10]; const float* tb1=(const float*)d_in[11];
  const float* tw2=(const float*)d_in[12]; const float* tb2=(const float*)d_in[13];
  const float* headq=(const float*)d_in[14];
  const float* fw1=(const float*)d_in[15];
  const float* fb1=(const float*)d_in[16];
  const float* fw2=(const float*)d_in[17];
  const float* fb2=(const float*)d_in[18];

  float* ueW = (float*)d_ws;                 // 262144 floats (1 MB)
  float* QhW = ueW + 262144;                 // 1024 floats
  half_t* Kg = (half_t*)(QhW + 1024);        // 524288 halves (1 MB)

  float* out = (float*)d_out;

  hipLaunchKernelGGL(enc_mfma, dim3(49), dim3(256), 0, stream,
      uav, task, uw0, ub0, uw1, ub1, uw2, ub2,
      tw0, tb0, tw1, tb1, tw2, tb2, headq, fw1,
      ueW, Kg, QhW);
  hipLaunchKernelGGL(logits_kernel, dim3(U_/UTILE, H_, B_), dim3(256), 0, stream,
      ueW, QhW, Kg, fb1, fw2, fb2, out);
}